// Round 1
// baseline (905.742 us; speedup 1.0000x reference)
//
#include <hip/hip_runtime.h>
#include <hip/hip_bf16.h>
#include <math.h>

// Problem constants (fixed by setup_inputs)
#define BATCH 512
#define NADV  16
#define NROWS (BATCH*NADV)     // 8192
#define DS    32
#define DO    32
#define DIM   64               // DS + DO
#define HID   128
#define WCOLS (DIM*HID)        // 8192 columns of hw2

// ---------------------------------------------------------------------------
// Kernel A: build mlp_input x[N,64] (obs[n%512] ++ latent_flat[n]) and
// h[N,128] = relu(x @ hw1 + hb1)
// ---------------------------------------------------------------------------
__global__ __launch_bounds__(128)
void k_input_h(const float* __restrict__ obs, const float* __restrict__ latent,
               const float* __restrict__ hw1, const float* __restrict__ hb1,
               float* __restrict__ xbuf, float* __restrict__ hbuf) {
    __shared__ float xs[16][DIM];
    int n0 = blockIdx.x * 16;
    int tid = threadIdx.x;
    for (int idx = tid; idx < 16 * DIM; idx += 128) {
        int r = idx >> 6, d = idx & 63;
        int n = n0 + r;
        // NOTE: reference pairs obs[n % B] with latent_flat[n] (torch .repeat
        // tiles batch dim, reshape(-1,DO) is row-major) — replicate exactly.
        float v = (d < DS) ? obs[(n & (BATCH - 1)) * DS + d]
                           : latent[(size_t)n * DO + (d - DS)];
        xs[r][d] = v;
        xbuf[(size_t)n * DIM + d] = v;
    }
    __syncthreads();
    int j = tid;  // 0..127
    float acc[16];
    float b = hb1[j];
#pragma unroll
    for (int r = 0; r < 16; ++r) acc[r] = b;
    for (int d = 0; d < DIM; ++d) {
        float w = hw1[d * HID + j];
#pragma unroll
        for (int r = 0; r < 16; ++r) acc[r] = fmaf(xs[r][d], w, acc[r]);
    }
#pragma unroll
    for (int r = 0; r < 16; ++r)
        hbuf[(size_t)(n0 + r) * HID + j] = fmaxf(acc[r], 0.f);
}

// ---------------------------------------------------------------------------
// Kernel B (dominant, 17.2 GFLOP): fused hypernet layer-2 + weighted d-reduce
// emb[n,j] = tanh( sum_d x[n,d] * relu( h[n,:] @ hw2[:, d*128+j] + hb2[d*128+j] ) )
// Block: 512 threads, 32 rows, all 8192 columns (d-reduction block-local,
// emb accumulator lives in registers — no atomics, no [N,8192] materialization).
// ---------------------------------------------------------------------------
__global__ __launch_bounds__(512)
void k_hyper(const float* __restrict__ xbuf, const float* __restrict__ hbuf,
             const float* __restrict__ hw2, const float* __restrict__ hb2,
             float* __restrict__ embbuf) {
    __shared__ float hs[32][HID];   // 16 KB
    __shared__ float xsh[32][DIM];  // 8 KB
    int n0 = blockIdx.x * 32;
    int tid = threadIdx.x;
    {
        const float4* src = (const float4*)(hbuf + (size_t)n0 * HID);
        float4* dst = (float4*)&hs[0][0];
        for (int i = tid; i < 32 * HID / 4; i += 512) dst[i] = src[i];
        const float4* sx = (const float4*)(xbuf + (size_t)n0 * DIM);
        float4* dx = (float4*)&xsh[0][0];
        for (int i = tid; i < 32 * DIM / 4; i += 512) dx[i] = sx[i];
    }
    __syncthreads();

    int tm = tid & 31;   // column group: j0 = tm*4
    int rg = tid >> 5;   // row group 0..15: rows r0, r0+1
    int j0 = tm * 4;
    int r0 = rg * 2;

    float acc_emb[2][4] = {{0.f, 0.f, 0.f, 0.f}, {0.f, 0.f, 0.f, 0.f}};

    for (int d = 0; d < DIM; ++d) {
        float acc[2][4] = {{0.f, 0.f, 0.f, 0.f}, {0.f, 0.f, 0.f, 0.f}};
        const float* wbase = hw2 + d * HID + j0;
#pragma unroll 8
        for (int k = 0; k < HID; k += 4) {
            float wv[16];
#pragma unroll
            for (int kk = 0; kk < 4; ++kk) {
                float4 t = *(const float4*)(wbase + (size_t)(k + kk) * WCOLS);
                wv[kk * 4 + 0] = t.x; wv[kk * 4 + 1] = t.y;
                wv[kk * 4 + 2] = t.z; wv[kk * 4 + 3] = t.w;
            }
#pragma unroll
            for (int r = 0; r < 2; ++r) {
                float4 hv4 = *(const float4*)(&hs[r0 + r][k]);
                float hv[4] = {hv4.x, hv4.y, hv4.z, hv4.w};
#pragma unroll
                for (int kk = 0; kk < 4; ++kk)
#pragma unroll
                    for (int mm = 0; mm < 4; ++mm)
                        acc[r][mm] = fmaf(hv[kk], wv[kk * 4 + mm], acc[r][mm]);
            }
        }
        float4 bias = *(const float4*)(hb2 + d * HID + j0);
        float bb[4] = {bias.x, bias.y, bias.z, bias.w};
#pragma unroll
        for (int r = 0; r < 2; ++r) {
            float xv = xsh[r0 + r][d];
#pragma unroll
            for (int mm = 0; mm < 4; ++mm)
                acc_emb[r][mm] = fmaf(xv, fmaxf(acc[r][mm] + bb[mm], 0.f),
                                      acc_emb[r][mm]);
        }
    }
#pragma unroll
    for (int r = 0; r < 2; ++r) {
        float* o = embbuf + (size_t)(n0 + r0 + r) * HID + j0;
#pragma unroll
        for (int mm = 0; mm < 4; ++mm) o[mm] = tanhf(acc_emb[r][mm]);
    }
}

// ---------------------------------------------------------------------------
// Kernel C: vals = relu(relu(emb @ vw1 + vb1) @ vw2 + vb2)
// ---------------------------------------------------------------------------
__global__ __launch_bounds__(128)
void k_vals(const float* __restrict__ emb,
            const float* __restrict__ vw1, const float* __restrict__ vb1,
            const float* __restrict__ vw2, const float* __restrict__ vb2,
            float* __restrict__ vals) {
    __shared__ float es[16][HID];
    __shared__ float t1[16][HID];
    int n0 = blockIdx.x * 16;
    int tid = threadIdx.x;
    {
        const float4* src = (const float4*)(emb + (size_t)n0 * HID);
        float4* dst = (float4*)&es[0][0];
        for (int i = tid; i < 16 * HID / 4; i += 128) dst[i] = src[i];
    }
    __syncthreads();
    int j = tid;
    float acc[16];
    float b1 = vb1[j];
#pragma unroll
    for (int r = 0; r < 16; ++r) acc[r] = b1;
    for (int k = 0; k < HID; ++k) {
        float w = vw1[k * HID + j];
#pragma unroll
        for (int r = 0; r < 16; ++r) acc[r] = fmaf(es[r][k], w, acc[r]);
    }
#pragma unroll
    for (int r = 0; r < 16; ++r) t1[r][j] = fmaxf(acc[r], 0.f);
    __syncthreads();
    float b2 = vb2[j];
#pragma unroll
    for (int r = 0; r < 16; ++r) acc[r] = b2;
    for (int k = 0; k < HID; ++k) {
        float w = vw2[k * HID + j];
#pragma unroll
        for (int r = 0; r < 16; ++r) acc[r] = fmaf(t1[r][k], w, acc[r]);
    }
#pragma unroll
    for (int r = 0; r < 16; ++r)
        vals[(size_t)(n0 + r) * HID + j] = fmaxf(acc[r], 0.f);
}

// ---------------------------------------------------------------------------
// Kernel D: emb_mean[b] = mean over a of emb[b*16+a]   (groups are n//16)
// ---------------------------------------------------------------------------
__global__ __launch_bounds__(256)
void k_mean(const float* __restrict__ emb, float* __restrict__ emb_mean) {
    int idx = blockIdx.x * 256 + threadIdx.x;  // 0..65535
    int b = idx >> 7, j = idx & 127;
    float s = 0.f;
#pragma unroll
    for (int a = 0; a < NADV; ++a)
        s += emb[(size_t)(b * NADV + a) * HID + j];
    emb_mean[idx] = s * (1.f / NADV);
}

// ---------------------------------------------------------------------------
// Kernel E: scores[n] = L3(relu(L2(relu(L1(concat(emb[n], emb_mean[n%512]))))))
// ---------------------------------------------------------------------------
__global__ __launch_bounds__(128)
void k_att(const float* __restrict__ emb, const float* __restrict__ emb_mean,
           const float* __restrict__ aw1, const float* __restrict__ ab1,
           const float* __restrict__ aw2, const float* __restrict__ ab2,
           const float* __restrict__ aw3, const float* __restrict__ ab3,
           float* __restrict__ scores) {
    __shared__ float ain[16][2 * HID];
    __shared__ float t1[16][HID];
    __shared__ float t2[16][HID];
    int n0 = blockIdx.x * 16;
    int tid = threadIdx.x;
    for (int idx = tid; idx < 16 * 2 * HID; idx += 128) {
        int r = idx >> 8, c = idx & 255;
        int n = n0 + r;
        // NOTE: mean_rep[n] = emb_mean[n % B] (torch .repeat tiling) — exact.
        ain[r][c] = (c < HID)
            ? emb[(size_t)n * HID + c]
            : emb_mean[(size_t)(n & (BATCH - 1)) * HID + (c - HID)];
    }
    __syncthreads();
    int j = tid;
    float acc[16];
    float b1 = ab1[j];
#pragma unroll
    for (int r = 0; r < 16; ++r) acc[r] = b1;
    for (int k = 0; k < 2 * HID; ++k) {
        float w = aw1[k * HID + j];
#pragma unroll
        for (int r = 0; r < 16; ++r) acc[r] = fmaf(ain[r][k], w, acc[r]);
    }
#pragma unroll
    for (int r = 0; r < 16; ++r) t1[r][j] = fmaxf(acc[r], 0.f);
    __syncthreads();
    float b2 = ab2[j];
#pragma unroll
    for (int r = 0; r < 16; ++r) acc[r] = b2;
    for (int k = 0; k < HID; ++k) {
        float w = aw2[k * HID + j];
#pragma unroll
        for (int r = 0; r < 16; ++r) acc[r] = fmaf(t1[r][k], w, acc[r]);
    }
#pragma unroll
    for (int r = 0; r < 16; ++r) t2[r][j] = fmaxf(acc[r], 0.f);
    __syncthreads();
    if (tid < 16) {
        int r = tid;
        float s = ab3[0];
        for (int k = 0; k < HID; ++k) s = fmaf(t2[r][k], aw3[k], s);
        scores[n0 + r] = s;
    }
}

// ---------------------------------------------------------------------------
// Kernel F: softmax over a (per b), out[b] = sum_a att[a] * vals[b*16+a]
// ---------------------------------------------------------------------------
__global__ __launch_bounds__(128)
void k_out(const float* __restrict__ scores, const float* __restrict__ vals,
           float* __restrict__ out) {
    __shared__ float sc[NADV];
    int b = blockIdx.x;
    int tid = threadIdx.x;
    if (tid < NADV) sc[tid] = scores[b * NADV + tid];
    __syncthreads();
    float m = -1e30f;
#pragma unroll
    for (int a = 0; a < NADV; ++a) m = fmaxf(m, sc[a]);
    float e[NADV];
    float S = 0.f;
#pragma unroll
    for (int a = 0; a < NADV; ++a) { e[a] = expf(sc[a] - m); S += e[a]; }
    float inv = 1.f / S;
    int j = tid;
    float o = 0.f;
#pragma unroll
    for (int a = 0; a < NADV; ++a)
        o = fmaf(e[a] * inv, vals[(size_t)(b * NADV + a) * HID + j], o);
    out[(size_t)b * HID + j] = o;
}

// ---------------------------------------------------------------------------
extern "C" void kernel_launch(void* const* d_in, const int* in_sizes, int n_in,
                              void* d_out, int out_size, void* d_ws, size_t ws_size,
                              hipStream_t stream) {
    const float* obs = (const float*)d_in[0];
    const float* lat = (const float*)d_in[1];
    const float* hw1 = (const float*)d_in[2];
    const float* hb1 = (const float*)d_in[3];
    const float* hw2 = (const float*)d_in[4];
    const float* hb2 = (const float*)d_in[5];
    const float* vw1 = (const float*)d_in[6];
    const float* vb1 = (const float*)d_in[7];
    const float* vw2 = (const float*)d_in[8];
    const float* vb2 = (const float*)d_in[9];
    const float* aw1 = (const float*)d_in[10];
    const float* ab1 = (const float*)d_in[11];
    const float* aw2 = (const float*)d_in[12];
    const float* ab2 = (const float*)d_in[13];
    const float* aw3 = (const float*)d_in[14];
    const float* ab3 = (const float*)d_in[15];
    float* out = (float*)d_out;

    float* ws = (float*)d_ws;
    float* xbuf   = ws;                                  // 8192*64
    float* hbuf   = xbuf   + (size_t)NROWS * DIM;        // 8192*128
    float* embbuf = hbuf   + (size_t)NROWS * HID;        // 8192*128
    float* vals   = embbuf + (size_t)NROWS * HID;        // 8192*128
    float* emean  = vals   + (size_t)NROWS * HID;        // 512*128
    float* scores = emean  + (size_t)BATCH * HID;        // 8192
    // total ≈ 15 MB of d_ws

    hipLaunchKernelGGL(k_input_h, dim3(NROWS / 16), dim3(128), 0, stream,
                       obs, lat, hw1, hb1, xbuf, hbuf);
    hipLaunchKernelGGL(k_hyper, dim3(NROWS / 32), dim3(512), 0, stream,
                       xbuf, hbuf, hw2, hb2, embbuf);
    hipLaunchKernelGGL(k_vals, dim3(NROWS / 16), dim3(128), 0, stream,
                       embbuf, vw1, vb1, vw2, vb2, vals);
    hipLaunchKernelGGL(k_mean, dim3(BATCH * HID / 256), dim3(256), 0, stream,
                       embbuf, emean);
    hipLaunchKernelGGL(k_att, dim3(NROWS / 16), dim3(128), 0, stream,
                       embbuf, emean, aw1, ab1, aw2, ab2, aw3, ab3, scores);
    hipLaunchKernelGGL(k_out, dim3(BATCH), dim3(128), 0, stream,
                       scores, vals, out);
}

// Round 2
// 290.403 us; speedup vs baseline: 3.1189x; 3.1189x over previous
//
#include <hip/hip_runtime.h>
#include <hip/hip_bf16.h>
#include <math.h>

// Problem constants (fixed by setup_inputs)
#define BATCH 512
#define NADV  16
#define NROWS (BATCH*NADV)     // 8192
#define DS    32
#define DO    32
#define DIM   64               // DS + DO
#define HID   128
#define WCOLS (DIM*HID)        // 8192 columns of hw2

typedef _Float16 half8 __attribute__((ext_vector_type(8)));
typedef float floatx4 __attribute__((ext_vector_type(4)));

// ---------------------------------------------------------------------------
// Kernel P: transpose + f16-convert hw2 [128 x 8192] -> w2t [8192 x 128]
// so MFMA B-fragments (8 consecutive k per lane) are single 16-B loads.
// ---------------------------------------------------------------------------
__global__ __launch_bounds__(256)
void k_prep_w(const float* __restrict__ hw2, _Float16* __restrict__ w2t) {
    __shared__ float tile[32][33];
    int j0 = (blockIdx.x & 255) * 32;   // 256 j-tiles
    int k0 = (blockIdx.x >> 8) * 32;    // 4 k-tiles
    int tx = threadIdx.x & 31, ty = threadIdx.x >> 5;  // ty 0..7
#pragma unroll
    for (int it = 0; it < 4; ++it) {
        int k = k0 + ty + it * 8;
        tile[tx][ty + it * 8] = hw2[(size_t)k * WCOLS + j0 + tx];
    }
    __syncthreads();
#pragma unroll
    for (int it = 0; it < 4; ++it) {
        int jl = ty + it * 8;
        w2t[(size_t)(j0 + jl) * HID + k0 + tx] = (_Float16)tile[jl][tx];
    }
}

// ---------------------------------------------------------------------------
// Kernel A: build mlp_input x[N,64] (obs[n%512] ++ latent_flat[n]) and
// h[N,128] = relu(x @ hw1 + hb1), stored as f16 (MFMA A operand).
// ---------------------------------------------------------------------------
__global__ __launch_bounds__(128)
void k_input_h(const float* __restrict__ obs, const float* __restrict__ latent,
               const float* __restrict__ hw1, const float* __restrict__ hb1,
               float* __restrict__ xbuf, _Float16* __restrict__ hf) {
    __shared__ float xs[16][DIM];
    int n0 = blockIdx.x * 16;
    int tid = threadIdx.x;
    for (int idx = tid; idx < 16 * DIM; idx += 128) {
        int r = idx >> 6, d = idx & 63;
        int n = n0 + r;
        // reference pairs obs[n % B] with latent_flat[n] (torch .repeat tiles
        // the batch dim; reshape(-1,DO) is row-major) — replicate exactly.
        float v = (d < DS) ? obs[(n & (BATCH - 1)) * DS + d]
                           : latent[(size_t)n * DO + (d - DS)];
        xs[r][d] = v;
        xbuf[(size_t)n * DIM + d] = v;
    }
    __syncthreads();
    int j = tid;  // 0..127
    float acc[16];
    float b = hb1[j];
#pragma unroll
    for (int r = 0; r < 16; ++r) acc[r] = b;
    for (int d = 0; d < DIM; ++d) {
        float w = hw1[d * HID + j];
#pragma unroll
        for (int r = 0; r < 16; ++r) acc[r] = fmaf(xs[r][d], w, acc[r]);
    }
#pragma unroll
    for (int r = 0; r < 16; ++r)
        hf[(size_t)(n0 + r) * HID + j] = (_Float16)fmaxf(acc[r], 0.f);
}

// ---------------------------------------------------------------------------
// Kernel B (dominant): MFMA f16 hypernet layer-2, fully fused epilogue.
// emb[n,jj] = tanh( sum_d x[n,d] * relu( h[n,:]@hw2[:,d*128+jj] + hb2 ) )
// Block: 8 waves, 32 rows, all 8192 cols (d-reduce block-local).
// A (h rows) resident in registers; B (w2t) streamed from L2; bias folded
// into MFMA C-init. Per-wave emb partials in 64 regs, merged via LDS atomics.
// ---------------------------------------------------------------------------
__global__ __launch_bounds__(512, 2)
void k_hyper_mfma(const float* __restrict__ xbuf, const _Float16* __restrict__ hf,
                  const _Float16* __restrict__ w2t, const float* __restrict__ hb2,
                  float* __restrict__ embbuf) {
    __shared__ float xsh[32][DIM];    // 8 KB
    __shared__ float emb_s[32][HID];  // 16 KB
    int n0 = blockIdx.x * 32;
    int tid = threadIdx.x;
    int wave = tid >> 6;      // 0..7: owns cols [wave*1024, wave*1024+1024)
    int lane = tid & 63;
    int l15 = lane & 15;
    int quad = lane >> 4;     // 0..3

    {
        const float4* sx = (const float4*)(xbuf + (size_t)n0 * DIM);
        float4* dx = (float4*)&xsh[0][0];
        for (int i = tid; i < 32 * DIM / 4; i += 512) dx[i] = sx[i];
        float4* dz = (float4*)&emb_s[0][0];
        float4 z = {0.f, 0.f, 0.f, 0.f};
        for (int i = tid; i < 32 * HID / 4; i += 512) dz[i] = z;
    }
    __syncthreads();

    // A fragments: lane holds A[m=l15 (+16*rt)][k=ks*32+quad*8 .. +7]
    half8 afrag[2][4];
#pragma unroll
    for (int rt = 0; rt < 2; ++rt)
#pragma unroll
        for (int ks = 0; ks < 4; ++ks)
            afrag[rt][ks] = *(const half8*)(hf + (size_t)(n0 + rt * 16 + l15) * HID
                                            + ks * 32 + quad * 8);

    float emb_acc[2][8][4];  // [row-tile][col-phase t][reg]
#pragma unroll
    for (int rt = 0; rt < 2; ++rt)
#pragma unroll
        for (int t = 0; t < 8; ++t)
#pragma unroll
            for (int reg = 0; reg < 4; ++reg) emb_acc[rt][t][reg] = 0.f;

    int c0 = wave * 1024;
    for (int d8 = 0; d8 < 8; ++d8) {       // this wave's d = wave*8 + d8
        int dd = wave * 8 + d8;
        float xv0[4], xv1[4];
#pragma unroll
        for (int reg = 0; reg < 4; ++reg) {
            xv0[reg] = xsh[quad * 4 + reg][dd];
            xv1[reg] = xsh[16 + quad * 4 + reg][dd];
        }
#pragma unroll
        for (int t = 0; t < 8; ++t) {
            int j0 = c0 + (d8 * 8 + t) * 16;
            const _Float16* bp = w2t + (size_t)(j0 + l15) * HID + quad * 8;
            float bb = hb2[j0 + l15];      // bias per col -> C-init
            floatx4 d0 = {bb, bb, bb, bb};
            floatx4 d1 = {bb, bb, bb, bb};
#pragma unroll
            for (int ks = 0; ks < 4; ++ks) {
                half8 b = *(const half8*)(bp + ks * 32);
                d0 = __builtin_amdgcn_mfma_f32_16x16x32_f16(afrag[0][ks], b, d0, 0, 0, 0);
                d1 = __builtin_amdgcn_mfma_f32_16x16x32_f16(afrag[1][ks], b, d1, 0, 0, 0);
            }
            // D layout: col = l15, row = quad*4 + reg (+16*rt)
#pragma unroll
            for (int reg = 0; reg < 4; ++reg) {
                emb_acc[0][t][reg] = fmaf(xv0[reg], fmaxf(d0[reg], 0.f), emb_acc[0][t][reg]);
                emb_acc[1][t][reg] = fmaf(xv1[reg], fmaxf(d1[reg], 0.f), emb_acc[1][t][reg]);
            }
        }
    }
    // merge 8 waves' partial emb (each covers disjoint d-range) via LDS atomics
#pragma unroll
    for (int rt = 0; rt < 2; ++rt)
#pragma unroll
        for (int t = 0; t < 8; ++t)
#pragma unroll
            for (int reg = 0; reg < 4; ++reg)
                atomicAdd(&emb_s[rt * 16 + quad * 4 + reg][t * 16 + l15],
                          emb_acc[rt][t][reg]);
    __syncthreads();
    for (int i = tid; i < 32 * HID; i += 512) {
        int r = i >> 7, c = i & 127;
        embbuf[(size_t)(n0 + r) * HID + c] = tanhf(emb_s[r][c]);
    }
}

// ---------------------------------------------------------------------------
// Kernel C: vals = relu(relu(emb @ vw1 + vb1) @ vw2 + vb2)
// ---------------------------------------------------------------------------
__global__ __launch_bounds__(128)
void k_vals(const float* __restrict__ emb,
            const float* __restrict__ vw1, const float* __restrict__ vb1,
            const float* __restrict__ vw2, const float* __restrict__ vb2,
            float* __restrict__ vals) {
    __shared__ float es[16][HID];
    __shared__ float t1[16][HID];
    int n0 = blockIdx.x * 16;
    int tid = threadIdx.x;
    {
        const float4* src = (const float4*)(emb + (size_t)n0 * HID);
        float4* dst = (float4*)&es[0][0];
        for (int i = tid; i < 16 * HID / 4; i += 128) dst[i] = src[i];
    }
    __syncthreads();
    int j = tid;
    float acc[16];
    float b1 = vb1[j];
#pragma unroll
    for (int r = 0; r < 16; ++r) acc[r] = b1;
    for (int k = 0; k < HID; ++k) {
        float w = vw1[k * HID + j];
#pragma unroll
        for (int r = 0; r < 16; ++r) acc[r] = fmaf(es[r][k], w, acc[r]);
    }
#pragma unroll
    for (int r = 0; r < 16; ++r) t1[r][j] = fmaxf(acc[r], 0.f);
    __syncthreads();
    float b2 = vb2[j];
#pragma unroll
    for (int r = 0; r < 16; ++r) acc[r] = b2;
    for (int k = 0; k < HID; ++k) {
        float w = vw2[k * HID + j];
#pragma unroll
        for (int r = 0; r < 16; ++r) acc[r] = fmaf(t1[r][k], w, acc[r]);
    }
#pragma unroll
    for (int r = 0; r < 16; ++r)
        vals[(size_t)(n0 + r) * HID + j] = fmaxf(acc[r], 0.f);
}

// ---------------------------------------------------------------------------
// Kernel D: emb_mean[b] = mean over a of emb[b*16+a]
// ---------------------------------------------------------------------------
__global__ __launch_bounds__(256)
void k_mean(const float* __restrict__ emb, float* __restrict__ emb_mean) {
    int idx = blockIdx.x * 256 + threadIdx.x;  // 0..65535
    int b = idx >> 7, j = idx & 127;
    float s = 0.f;
#pragma unroll
    for (int a = 0; a < NADV; ++a)
        s += emb[(size_t)(b * NADV + a) * HID + j];
    emb_mean[idx] = s * (1.f / NADV);
}

// ---------------------------------------------------------------------------
// Kernel E: scores[n] = L3(relu(L2(relu(L1(concat(emb[n], emb_mean[n%512]))))))
// ---------------------------------------------------------------------------
__global__ __launch_bounds__(128)
void k_att(const float* __restrict__ emb, const float* __restrict__ emb_mean,
           const float* __restrict__ aw1, const float* __restrict__ ab1,
           const float* __restrict__ aw2, const float* __restrict__ ab2,
           const float* __restrict__ aw3, const float* __restrict__ ab3,
           float* __restrict__ scores) {
    __shared__ float ain[16][2 * HID];
    __shared__ float t1[16][HID];
    __shared__ float t2[16][HID];
    int n0 = blockIdx.x * 16;
    int tid = threadIdx.x;
    for (int idx = tid; idx < 16 * 2 * HID; idx += 128) {
        int r = idx >> 8, c = idx & 255;
        int n = n0 + r;
        // mean_rep[n] = emb_mean[n % B] (torch .repeat tiling) — exact.
        ain[r][c] = (c < HID)
            ? emb[(size_t)n * HID + c]
            : emb_mean[(size_t)(n & (BATCH - 1)) * HID + (c - HID)];
    }
    __syncthreads();
    int j = tid;
    float acc[16];
    float b1 = ab1[j];
#pragma unroll
    for (int r = 0; r < 16; ++r) acc[r] = b1;
    for (int k = 0; k < 2 * HID; ++k) {
        float w = aw1[k * HID + j];
#pragma unroll
        for (int r = 0; r < 16; ++r) acc[r] = fmaf(ain[r][k], w, acc[r]);
    }
#pragma unroll
    for (int r = 0; r < 16; ++r) t1[r][j] = fmaxf(acc[r], 0.f);
    __syncthreads();
    float b2 = ab2[j];
#pragma unroll
    for (int r = 0; r < 16; ++r) acc[r] = b2;
    for (int k = 0; k < HID; ++k) {
        float w = aw2[k * HID + j];
#pragma unroll
        for (int r = 0; r < 16; ++r) acc[r] = fmaf(t1[r][k], w, acc[r]);
    }
#pragma unroll
    for (int r = 0; r < 16; ++r) t2[r][j] = fmaxf(acc[r], 0.f);
    __syncthreads();
    if (tid < 16) {
        int r = tid;
        float s = ab3[0];
        for (int k = 0; k < HID; ++k) s = fmaf(t2[r][k], aw3[k], s);
        scores[n0 + r] = s;
    }
}

// ---------------------------------------------------------------------------
// Kernel F: softmax over a (per b), out[b] = sum_a att[a] * vals[b*16+a]
// ---------------------------------------------------------------------------
__global__ __launch_bounds__(128)
void k_out(const float* __restrict__ scores, const float* __restrict__ vals,
           float* __restrict__ out) {
    __shared__ float sc[NADV];
    int b = blockIdx.x;
    int tid = threadIdx.x;
    if (tid < NADV) sc[tid] = scores[b * NADV + tid];
    __syncthreads();
    float m = -1e30f;
#pragma unroll
    for (int a = 0; a < NADV; ++a) m = fmaxf(m, sc[a]);
    float e[NADV];
    float S = 0.f;
#pragma unroll
    for (int a = 0; a < NADV; ++a) { e[a] = expf(sc[a] - m); S += e[a]; }
    float inv = 1.f / S;
    int j = tid;
    float o = 0.f;
#pragma unroll
    for (int a = 0; a < NADV; ++a)
        o = fmaf(e[a] * inv, vals[(size_t)(b * NADV + a) * HID + j], o);
    out[(size_t)b * HID + j] = o;
}

// ---------------------------------------------------------------------------
extern "C" void kernel_launch(void* const* d_in, const int* in_sizes, int n_in,
                              void* d_out, int out_size, void* d_ws, size_t ws_size,
                              hipStream_t stream) {
    const float* obs = (const float*)d_in[0];
    const float* lat = (const float*)d_in[1];
    const float* hw1 = (const float*)d_in[2];
    const float* hb1 = (const float*)d_in[3];
    const float* hw2 = (const float*)d_in[4];
    const float* hb2 = (const float*)d_in[5];
    const float* vw1 = (const float*)d_in[6];
    const float* vb1 = (const float*)d_in[7];
    const float* vw2 = (const float*)d_in[8];
    const float* vb2 = (const float*)d_in[9];
    const float* aw1 = (const float*)d_in[10];
    const float* ab1 = (const float*)d_in[11];
    const float* aw2 = (const float*)d_in[12];
    const float* ab2 = (const float*)d_in[13];
    const float* aw3 = (const float*)d_in[14];
    const float* ab3 = (const float*)d_in[15];
    float* out = (float*)d_out;

    char* ws = (char*)d_ws;
    float*     xbuf   = (float*)ws;                    ws += (size_t)NROWS * DIM * 4;   // 2 MB
    _Float16*  hf     = (_Float16*)ws;                 ws += (size_t)NROWS * HID * 2;   // 2 MB
    _Float16*  w2t    = (_Float16*)ws;                 ws += (size_t)WCOLS * HID * 2;   // 2 MB
    float*     embbuf = (float*)ws;                    ws += (size_t)NROWS * HID * 4;   // 4 MB
    float*     vals   = (float*)ws;                    ws += (size_t)NROWS * HID * 4;   // 4 MB
    float*     emean  = (float*)ws;                    ws += (size_t)BATCH * HID * 4;
    float*     scores = (float*)ws;                    ws += (size_t)NROWS * 4;

    hipLaunchKernelGGL(k_prep_w, dim3(256 * 4), dim3(256), 0, stream, hw2, w2t);
    hipLaunchKernelGGL(k_input_h, dim3(NROWS / 16), dim3(128), 0, stream,
                       obs, lat, hw1, hb1, xbuf, hf);
    hipLaunchKernelGGL(k_hyper_mfma, dim3(NROWS / 32), dim3(512), 0, stream,
                       xbuf, hf, w2t, hb2, embbuf);
    hipLaunchKernelGGL(k_vals, dim3(NROWS / 16), dim3(128), 0, stream,
                       embbuf, vw1, vb1, vw2, vb2, vals);
    hipLaunchKernelGGL(k_mean, dim3(BATCH * HID / 256), dim3(256), 0, stream,
                       embbuf, emean);
    hipLaunchKernelGGL(k_att, dim3(NROWS / 16), dim3(128), 0, stream,
                       embbuf, emean, aw1, ab1, aw2, ab2, aw3, ab3, scores);
    hipLaunchKernelGGL(k_out, dim3(BATCH), dim3(128), 0, stream,
                       scores, vals, out);
}

// Round 3
// 232.797 us; speedup vs baseline: 3.8907x; 1.2475x over previous
//
#include <hip/hip_runtime.h>
#include <hip/hip_bf16.h>
#include <math.h>

// Problem constants (fixed by setup_inputs)
#define BATCH 512
#define NADV  16
#define NROWS (BATCH*NADV)     // 8192
#define DS    32
#define DO    32
#define DIM   64               // DS + DO
#define HID   128
#define WCOLS (DIM*HID)        // 8192 columns of hw2
#define LSTR  136              // padded f16 LDS row stride (2-way bank aliasing)

typedef _Float16 half8 __attribute__((ext_vector_type(8)));
typedef float floatx4 __attribute__((ext_vector_type(4)));

// ---------------------------------------------------------------------------
// Kernel P: pack W[K x N] (fp32, k-major) into MFMA-native f16 chunks:
// dst[((ct*Kt + kt)*64 + lane)*8 + e] = W[kt*32 + (lane>>4)*8 + e][ct*16 + (lane&15)]
// so a wave's B-fragment load is ONE contiguous 1 KB burst (lane*16 B).
// Handles hw2 (512 ct-tiles) + vw1/vw2/aw1/aw2 in one launch.
// ---------------------------------------------------------------------------
__global__ __launch_bounds__(256)
void k_pack(const float* __restrict__ hw2, const float* __restrict__ vw1,
            const float* __restrict__ vw2, const float* __restrict__ aw1,
            const float* __restrict__ aw2,
            _Float16* __restrict__ w2p, _Float16* __restrict__ vw1p,
            _Float16* __restrict__ vw2p, _Float16* __restrict__ aw1p,
            _Float16* __restrict__ aw2p) {
    __shared__ float tile[256][17];
    int b = blockIdx.x;
    const float* src; _Float16* dst; int N, Kt, ct;
    if (b < 512)      { src = hw2; dst = w2p;  N = WCOLS; Kt = 4; ct = b; }
    else if (b < 520) { src = vw1; dst = vw1p; N = HID;   Kt = 4; ct = b - 512; }
    else if (b < 528) { src = vw2; dst = vw2p; N = HID;   Kt = 4; ct = b - 520; }
    else if (b < 536) { src = aw1; dst = aw1p; N = HID;   Kt = 8; ct = b - 528; }
    else              { src = aw2; dst = aw2p; N = HID;   Kt = 4; ct = b - 536; }
    int rows = Kt * 32;
    int tid = threadIdx.x;
    int c = tid & 15;
    for (int r = tid >> 4; r < rows; r += 16)
        tile[r][c] = src[(size_t)r * N + ct * 16 + c];
    __syncthreads();
    for (int idx = tid; idx < rows * 16; idx += 256) {
        int e = idx & 7, lane = (idx >> 3) & 63, kt = idx >> 9;
        dst[((size_t)ct * Kt + kt) * 512 + lane * 8 + e] =
            (_Float16)tile[kt * 32 + (lane >> 4) * 8 + e][lane & 15];
    }
}

// ---------------------------------------------------------------------------
// Kernel A: build mlp_input x[N,64] (obs[n%512] ++ latent_flat[n]) and
// h[N,128] = relu(x @ hw1 + hb1), stored as f16 (MFMA A operand).
// ---------------------------------------------------------------------------
__global__ __launch_bounds__(128)
void k_input_h(const float* __restrict__ obs, const float* __restrict__ latent,
               const float* __restrict__ hw1, const float* __restrict__ hb1,
               float* __restrict__ xbuf, _Float16* __restrict__ hf) {
    __shared__ float xs[16][DIM];
    int n0 = blockIdx.x * 16;
    int tid = threadIdx.x;
    for (int idx = tid; idx < 16 * DIM; idx += 128) {
        int r = idx >> 6, d = idx & 63;
        int n = n0 + r;
        // reference pairs obs[n % B] with latent_flat[n] (torch .repeat tiles
        // the batch dim; reshape(-1,DO) is row-major) — replicate exactly.
        float v = (d < DS) ? obs[(n & (BATCH - 1)) * DS + d]
                           : latent[(size_t)n * DO + (d - DS)];
        xs[r][d] = v;
        xbuf[(size_t)n * DIM + d] = v;
    }
    __syncthreads();
    int j = tid;  // 0..127
    float acc[16];
    float b = hb1[j];
#pragma unroll
    for (int r = 0; r < 16; ++r) acc[r] = b;
    for (int d = 0; d < DIM; ++d) {
        float w = hw1[d * HID + j];
#pragma unroll
        for (int r = 0; r < 16; ++r) acc[r] = fmaf(xs[r][d], w, acc[r]);
    }
#pragma unroll
    for (int r = 0; r < 16; ++r)
        hf[(size_t)(n0 + r) * HID + j] = (_Float16)fmaxf(acc[r], 0.f);
}

// ---------------------------------------------------------------------------
// Kernel B (dominant): MFMA f16 hypernet layer-2, fused epilogue, with
// MFMA-native packed B so every B-load is one contiguous 1 KB wave burst.
// emb[n,jj] = tanh( sum_d x[n,d] * relu( h[n,:]@hw2[:,d*128+jj] + hb2 ) )
// ---------------------------------------------------------------------------
__global__ __launch_bounds__(512, 2)
void k_hyper_mfma(const float* __restrict__ xbuf, const _Float16* __restrict__ hf,
                  const _Float16* __restrict__ w2p, const float* __restrict__ hb2,
                  _Float16* __restrict__ embf) {
    __shared__ float xsh[32][DIM];    // 8 KB
    __shared__ float emb_s[32][HID];  // 16 KB
    int n0 = blockIdx.x * 32;
    int tid = threadIdx.x;
    int wave = tid >> 6;      // 0..7: owns cols [wave*1024, +1024) => d in [wave*8, +8)
    int lane = tid & 63;
    int l15 = lane & 15;
    int quad = lane >> 4;

    {
        const float4* sx = (const float4*)(xbuf + (size_t)n0 * DIM);
        float4* dx = (float4*)&xsh[0][0];
        for (int i = tid; i < 32 * DIM / 4; i += 512) dx[i] = sx[i];
        float4* dz = (float4*)&emb_s[0][0];
        float4 z = {0.f, 0.f, 0.f, 0.f};
        for (int i = tid; i < 32 * HID / 4; i += 512) dz[i] = z;
    }
    __syncthreads();

    // A fragments: lane holds A[m=l15 (+16*rt)][k=ks*32+quad*8 .. +7]
    half8 afrag[2][4];
#pragma unroll
    for (int rt = 0; rt < 2; ++rt)
#pragma unroll
        for (int ks = 0; ks < 4; ++ks)
            afrag[rt][ks] = *(const half8*)(hf + (size_t)(n0 + rt * 16 + l15) * HID
                                            + ks * 32 + quad * 8);

    float emb_acc[2][8][4];  // [row-tile][col-phase t][reg]
#pragma unroll
    for (int rt = 0; rt < 2; ++rt)
#pragma unroll
        for (int t = 0; t < 8; ++t)
#pragma unroll
            for (int reg = 0; reg < 4; ++reg) emb_acc[rt][t][reg] = 0.f;

    for (int d8 = 0; d8 < 8; ++d8) {       // this wave's d = wave*8 + d8
        int dd = wave * 8 + d8;
        float xv0[4], xv1[4];
#pragma unroll
        for (int reg = 0; reg < 4; ++reg) {
            xv0[reg] = xsh[quad * 4 + reg][dd];
            xv1[reg] = xsh[16 + quad * 4 + reg][dd];
        }
#pragma unroll
        for (int t = 0; t < 8; ++t) {
            int ct = wave * 64 + d8 * 8 + t;           // 16-col tile index
            const _Float16* bp = w2p + (size_t)ct * 2048 + lane * 8;
            float bb = hb2[ct * 16 + l15];             // bias per col -> C-init
            floatx4 d0 = {bb, bb, bb, bb};
            floatx4 d1 = {bb, bb, bb, bb};
#pragma unroll
            for (int ks = 0; ks < 4; ++ks) {
                half8 b = *(const half8*)(bp + ks * 512);   // 1 KB wave burst
                d0 = __builtin_amdgcn_mfma_f32_16x16x32_f16(afrag[0][ks], b, d0, 0, 0, 0);
                d1 = __builtin_amdgcn_mfma_f32_16x16x32_f16(afrag[1][ks], b, d1, 0, 0, 0);
            }
            // D layout: col = l15, row = quad*4 + reg (+16*rt)
#pragma unroll
            for (int reg = 0; reg < 4; ++reg) {
                emb_acc[0][t][reg] = fmaf(xv0[reg], fmaxf(d0[reg], 0.f), emb_acc[0][t][reg]);
                emb_acc[1][t][reg] = fmaf(xv1[reg], fmaxf(d1[reg], 0.f), emb_acc[1][t][reg]);
            }
        }
    }
    // merge 8 waves' disjoint-d partials via LDS atomics
#pragma unroll
    for (int rt = 0; rt < 2; ++rt)
#pragma unroll
        for (int t = 0; t < 8; ++t)
#pragma unroll
            for (int reg = 0; reg < 4; ++reg)
                atomicAdd(&emb_s[rt * 16 + quad * 4 + reg][t * 16 + l15],
                          emb_acc[rt][t][reg]);
    __syncthreads();
    for (int i = tid; i < 32 * HID; i += 512) {
        int r = i >> 7, c = i & 127;
        embf[(size_t)(n0 + r) * HID + c] = (_Float16)tanhf(emb_s[r][c]);
    }
}

// ---------------------------------------------------------------------------
// Kernel D: emb_mean[b] = mean over a of emb[b*16+a], f16 out
// ---------------------------------------------------------------------------
__global__ __launch_bounds__(256)
void k_mean(const _Float16* __restrict__ embf, _Float16* __restrict__ emeanf) {
    int idx = blockIdx.x * 256 + threadIdx.x;  // 0..65535
    int b = idx >> 7, j = idx & 127;
    float s = 0.f;
#pragma unroll
    for (int a = 0; a < NADV; ++a)
        s += (float)embf[(size_t)(b * NADV + a) * HID + j];
    emeanf[idx] = (_Float16)(s * (1.f / NADV));
}

// ---------------------------------------------------------------------------
// Kernel T (fused tail): per block of 32 rows (= 2 softmax groups):
//   vals = relu(relu(emb@vw1+b)@vw2+b)            [MFMA, regs]
//   scores = relu(relu([emb|mean]@aw1+b)@aw2+b)@aw3+b   [MFMA + dot]
//   att = softmax over 16-row group; out[g] = sum_a att*vals
// Activations round-trip LDS (stride 136 f16: 2-way bank aliasing = free).
// ---------------------------------------------------------------------------
__global__ __launch_bounds__(256)
void k_tail(const _Float16* __restrict__ embf, const _Float16* __restrict__ emeanf,
            const _Float16* __restrict__ vw1p, const float* __restrict__ vb1,
            const _Float16* __restrict__ vw2p, const float* __restrict__ vb2,
            const _Float16* __restrict__ aw1p, const float* __restrict__ ab1,
            const _Float16* __restrict__ aw2p, const float* __restrict__ ab2,
            const float* __restrict__ aw3, const float* __restrict__ ab3,
            float* __restrict__ out) {
    __shared__ _Float16 embs[32][LSTR];
    __shared__ _Float16 means[32][LSTR];
    __shared__ _Float16 tAs[32][LSTR];
    __shared__ _Float16 tBs[32][LSTR];
    __shared__ float satt[32];
    __shared__ float att[32];
    __shared__ float scr[32][8];
    __shared__ float outacc[2][HID];
    int n0 = blockIdx.x * 32;
    int tid = threadIdx.x;
    int wave = tid >> 6, lane = tid & 63, l15 = lane & 15, quad = lane >> 4;
    int ct0 = wave * 2;   // this wave owns col-tiles ct0, ct0+1 (N=128 => 8 tiles)

    for (int i = tid; i < 32 * 16; i += 256) {
        int r = i >> 4, c8 = (i & 15) * 8;
        *(half8*)&embs[r][c8]  = *(const half8*)(embf  + (size_t)(n0 + r) * HID + c8);
        // mean_rep[n] = emb_mean[n % 512] (torch .repeat tiling) — exact.
        *(half8*)&means[r][c8] = *(const half8*)(emeanf + (size_t)((n0 & 511) + r) * HID + c8);
    }
    __syncthreads();

    half8 av[2][4], amean[2][4];
#pragma unroll
    for (int rt = 0; rt < 2; ++rt)
#pragma unroll
        for (int ks = 0; ks < 4; ++ks) {
            av[rt][ks]    = *(const half8*)&embs[rt * 16 + l15][ks * 32 + quad * 8];
            amean[rt][ks] = *(const half8*)&means[rt * 16 + l15][ks * 32 + quad * 8];
        }

    // ---- v1: t1 = relu(emb @ vw1 + vb1) ----
    floatx4 acc[2][2];
#pragma unroll
    for (int ct2 = 0; ct2 < 2; ++ct2) {
        float bb = vb1[(ct0 + ct2) * 16 + l15];
#pragma unroll
        for (int rt = 0; rt < 2; ++rt) acc[rt][ct2] = (floatx4){bb, bb, bb, bb};
    }
#pragma unroll
    for (int ct2 = 0; ct2 < 2; ++ct2)
#pragma unroll
        for (int ks = 0; ks < 4; ++ks) {
            half8 bfr = *(const half8*)(vw1p + ((size_t)(ct0 + ct2) * 4 + ks) * 512 + lane * 8);
#pragma unroll
            for (int rt = 0; rt < 2; ++rt)
                acc[rt][ct2] = __builtin_amdgcn_mfma_f32_16x16x32_f16(av[rt][ks], bfr, acc[rt][ct2], 0, 0, 0);
        }
#pragma unroll
    for (int rt = 0; rt < 2; ++rt)
#pragma unroll
        for (int ct2 = 0; ct2 < 2; ++ct2)
#pragma unroll
            for (int reg = 0; reg < 4; ++reg)
                tAs[rt * 16 + quad * 4 + reg][(ct0 + ct2) * 16 + l15] =
                    (_Float16)fmaxf(acc[rt][ct2][reg], 0.f);
    __syncthreads();

    half8 at[2][4];
#pragma unroll
    for (int rt = 0; rt < 2; ++rt)
#pragma unroll
        for (int ks = 0; ks < 4; ++ks)
            at[rt][ks] = *(const half8*)&tAs[rt * 16 + l15][ks * 32 + quad * 8];

    // ---- v2: vals = relu(t1 @ vw2 + vb2), kept in registers ----
    floatx4 vacc[2][2];
#pragma unroll
    for (int ct2 = 0; ct2 < 2; ++ct2) {
        float bb = vb2[(ct0 + ct2) * 16 + l15];
#pragma unroll
        for (int rt = 0; rt < 2; ++rt) vacc[rt][ct2] = (floatx4){bb, bb, bb, bb};
    }
#pragma unroll
    for (int ct2 = 0; ct2 < 2; ++ct2)
#pragma unroll
        for (int ks = 0; ks < 4; ++ks) {
            half8 bfr = *(const half8*)(vw2p + ((size_t)(ct0 + ct2) * 4 + ks) * 512 + lane * 8);
#pragma unroll
            for (int rt = 0; rt < 2; ++rt)
                vacc[rt][ct2] = __builtin_amdgcn_mfma_f32_16x16x32_f16(at[rt][ks], bfr, vacc[rt][ct2], 0, 0, 0);
        }

    // ---- a1: ta1 = relu([emb|mean] @ aw1 + ab1), K=256 ----
    floatx4 aacc[2][2];
#pragma unroll
    for (int ct2 = 0; ct2 < 2; ++ct2) {
        float bb = ab1[(ct0 + ct2) * 16 + l15];
#pragma unroll
        for (int rt = 0; rt < 2; ++rt) aacc[rt][ct2] = (floatx4){bb, bb, bb, bb};
    }
#pragma unroll
    for (int ct2 = 0; ct2 < 2; ++ct2)
#pragma unroll
        for (int ks = 0; ks < 8; ++ks) {
            half8 bfr = *(const half8*)(aw1p + ((size_t)(ct0 + ct2) * 8 + ks) * 512 + lane * 8);
#pragma unroll
            for (int rt = 0; rt < 2; ++rt) {
                half8 a = (ks < 4) ? av[rt][ks] : amean[rt][ks - 4];
                aacc[rt][ct2] = __builtin_amdgcn_mfma_f32_16x16x32_f16(a, bfr, aacc[rt][ct2], 0, 0, 0);
            }
        }
#pragma unroll
    for (int rt = 0; rt < 2; ++rt)
#pragma unroll
        for (int ct2 = 0; ct2 < 2; ++ct2)
#pragma unroll
            for (int reg = 0; reg < 4; ++reg)
                tBs[rt * 16 + quad * 4 + reg][(ct0 + ct2) * 16 + l15] =
                    (_Float16)fmaxf(aacc[rt][ct2][reg], 0.f);
    __syncthreads();

    half8 aa[2][4];
#pragma unroll
    for (int rt = 0; rt < 2; ++rt)
#pragma unroll
        for (int ks = 0; ks < 4; ++ks)
            aa[rt][ks] = *(const half8*)&tBs[rt * 16 + l15][ks * 32 + quad * 8];

    // ---- a2: t2 = relu(ta1 @ aw2 + ab2) -> tAs ----
    floatx4 a2acc[2][2];
#pragma unroll
    for (int ct2 = 0; ct2 < 2; ++ct2) {
        float bb = ab2[(ct0 + ct2) * 16 + l15];
#pragma unroll
        for (int rt = 0; rt < 2; ++rt) a2acc[rt][ct2] = (floatx4){bb, bb, bb, bb};
    }
#pragma unroll
    for (int ct2 = 0; ct2 < 2; ++ct2)
#pragma unroll
        for (int ks = 0; ks < 4; ++ks) {
            half8 bfr = *(const half8*)(aw2p + ((size_t)(ct0 + ct2) * 4 + ks) * 512 + lane * 8);
#pragma unroll
            for (int rt = 0; rt < 2; ++rt)
                a2acc[rt][ct2] = __builtin_amdgcn_mfma_f32_16x16x32_f16(aa[rt][ks], bfr, a2acc[rt][ct2], 0, 0, 0);
        }
#pragma unroll
    for (int rt = 0; rt < 2; ++rt)
#pragma unroll
        for (int ct2 = 0; ct2 < 2; ++ct2)
#pragma unroll
            for (int reg = 0; reg < 4; ++reg)
                tAs[rt * 16 + quad * 4 + reg][(ct0 + ct2) * 16 + l15] =
                    (_Float16)fmaxf(a2acc[rt][ct2][reg], 0.f);
    __syncthreads();

    // ---- scores: s[r] = t2[r,:] . aw3 + ab3 ----
    {
        int r = tid >> 3, ch = tid & 7;
        float p = 0.f;
#pragma unroll
        for (int k = 0; k < 16; ++k)
            p += (float)tAs[r][ch * 16 + k] * aw3[ch * 16 + k];
        scr[r][ch] = p;
    }
    __syncthreads();
    if (tid < 32) {
        float s = ab3[0];
#pragma unroll
        for (int ch = 0; ch < 8; ++ch) s += scr[tid][ch];
        satt[tid] = s;
    }
    __syncthreads();
    if (tid < 32) {
        int g = tid & ~15;
        float m = -1e30f;
#pragma unroll
        for (int a = 0; a < 16; ++a) m = fmaxf(m, satt[g + a]);
        float S = 0.f;
#pragma unroll
        for (int a = 0; a < 16; ++a) S += expf(satt[g + a] - m);
        att[tid] = expf(satt[tid] - m) / S;
    }
    __syncthreads();

    // ---- weighted sum: out[g, col] = sum_a att[a] * vals[a, col] ----
#pragma unroll
    for (int rt = 0; rt < 2; ++rt)
#pragma unroll
        for (int ct2 = 0; ct2 < 2; ++ct2) {
            float p = 0.f;
#pragma unroll
            for (int reg = 0; reg < 4; ++reg)
                p += att[rt * 16 + quad * 4 + reg] * fmaxf(vacc[rt][ct2][reg], 0.f);
            p += __shfl_xor(p, 16, 64);
            p += __shfl_xor(p, 32, 64);
            if (quad == 0) outacc[rt][(ct0 + ct2) * 16 + l15] = p;
        }
    __syncthreads();
    {
        int rt = tid >> 7, col = tid & 127;
        out[(size_t)((n0 >> 4) + rt) * HID + col] = outacc[rt][col];
    }
}

// ---------------------------------------------------------------------------
extern "C" void kernel_launch(void* const* d_in, const int* in_sizes, int n_in,
                              void* d_out, int out_size, void* d_ws, size_t ws_size,
                              hipStream_t stream) {
    const float* obs = (const float*)d_in[0];
    const float* lat = (const float*)d_in[1];
    const float* hw1 = (const float*)d_in[2];
    const float* hb1 = (const float*)d_in[3];
    const float* hw2 = (const float*)d_in[4];
    const float* hb2 = (const float*)d_in[5];
    const float* vw1 = (const float*)d_in[6];
    const float* vb1 = (const float*)d_in[7];
    const float* vw2 = (const float*)d_in[8];
    const float* vb2 = (const float*)d_in[9];
    const float* aw1 = (const float*)d_in[10];
    const float* ab1 = (const float*)d_in[11];
    const float* aw2 = (const float*)d_in[12];
    const float* ab2 = (const float*)d_in[13];
    const float* aw3 = (const float*)d_in[14];
    const float* ab3 = (const float*)d_in[15];
    float* out = (float*)d_out;

    char* ws = (char*)d_ws;
    float*     xbuf   = (float*)ws;     ws += (size_t)NROWS * DIM * 4;     // 2 MB
    _Float16*  hf     = (_Float16*)ws;  ws += (size_t)NROWS * HID * 2;     // 2 MB
    _Float16*  w2p    = (_Float16*)ws;  ws += (size_t)WCOLS * HID * 2;     // 2 MB
    _Float16*  embf   = (_Float16*)ws;  ws += (size_t)NROWS * HID * 2;     // 2 MB
    _Float16*  emeanf = (_Float16*)ws;  ws += (size_t)BATCH * HID * 2;     // 128 KB
    _Float16*  vw1p   = (_Float16*)ws;  ws += (size_t)HID * HID * 2;       // 32 KB
    _Float16*  vw2p   = (_Float16*)ws;  ws += (size_t)HID * HID * 2;
    _Float16*  aw1p   = (_Float16*)ws;  ws += (size_t)2 * HID * HID * 2;   // 64 KB
    _Float16*  aw2p   = (_Float16*)ws;  ws += (size_t)HID * HID * 2;

    hipLaunchKernelGGL(k_pack, dim3(544), dim3(256), 0, stream,
                       hw2, vw1, vw2, aw1, aw2, w2p, vw1p, vw2p, aw1p, aw2p);
    hipLaunchKernelGGL(k_input_h, dim3(NROWS / 16), dim3(128), 0, stream,
                       obs, lat, hw1, hb1, xbuf, hf);
    hipLaunchKernelGGL(k_hyper_mfma, dim3(NROWS / 32), dim3(512), 0, stream,
                       xbuf, hf, w2p, hb2, embf);
    hipLaunchKernelGGL(k_mean, dim3(BATCH * HID / 256), dim3(256), 0, stream,
                       embf, emeanf);
    hipLaunchKernelGGL(k_tail, dim3(NROWS / 32), dim3(256), 0, stream,
                       embf, emeanf, vw1p, vb1, vw2p, vb2,
                       aw1p, ab1, aw2p, ab2, aw3, ab3, out);
}

// Round 4
// 150.074 us; speedup vs baseline: 6.0353x; 1.5512x over previous
//
#include <hip/hip_runtime.h>
#include <hip/hip_bf16.h>
#include <math.h>

// Problem constants (fixed by setup_inputs)
#define BATCH 512
#define NADV  16
#define NROWS (BATCH*NADV)     // 8192
#define DS    32
#define DO    32
#define DIM   64               // DS + DO
#define HID   128
#define WCOLS (DIM*HID)        // 8192 columns of hw2
#define LSTR  136              // padded f16 LDS row stride (2-way bank aliasing)
#define DG    8                // d-values per k_hyper block (8 d-groups total)

typedef _Float16 half8 __attribute__((ext_vector_type(8)));
typedef float floatx4 __attribute__((ext_vector_type(4)));

__device__ inline void async_ld16(void* lds, const void* g) {
    __builtin_amdgcn_global_load_lds(
        (const __attribute__((address_space(1))) void*)g,
        (__attribute__((address_space(3))) void*)lds, 16, 0, 0);
}

// ---------------------------------------------------------------------------
// Kernel P: pack W[K x N] (fp32, k-major) into MFMA-native f16 chunks:
// dst[((ct*Kt + kt)*64 + lane)*8 + e] = W[kt*32 + (lane>>4)*8 + e][ct*16 + (lane&15)]
// so a wave's B-fragment load is ONE contiguous 1 KB burst (lane*16 B).
// ---------------------------------------------------------------------------
__global__ __launch_bounds__(256)
void k_pack(const float* __restrict__ hw2, const float* __restrict__ vw1,
            const float* __restrict__ vw2, const float* __restrict__ aw1,
            const float* __restrict__ aw2,
            _Float16* __restrict__ w2p, _Float16* __restrict__ vw1p,
            _Float16* __restrict__ vw2p, _Float16* __restrict__ aw1p,
            _Float16* __restrict__ aw2p) {
    __shared__ float tile[256][17];
    int b = blockIdx.x;
    const float* src; _Float16* dst; int N, Kt, ct;
    if (b < 512)      { src = hw2; dst = w2p;  N = WCOLS; Kt = 4; ct = b; }
    else if (b < 520) { src = vw1; dst = vw1p; N = HID;   Kt = 4; ct = b - 512; }
    else if (b < 528) { src = vw2; dst = vw2p; N = HID;   Kt = 4; ct = b - 520; }
    else if (b < 536) { src = aw1; dst = aw1p; N = HID;   Kt = 8; ct = b - 528; }
    else              { src = aw2; dst = aw2p; N = HID;   Kt = 4; ct = b - 536; }
    int rows = Kt * 32;
    int tid = threadIdx.x;
    int c = tid & 15;
    for (int r = tid >> 4; r < rows; r += 16)
        tile[r][c] = src[(size_t)r * N + ct * 16 + c];
    __syncthreads();
    for (int idx = tid; idx < rows * 16; idx += 256) {
        int e = idx & 7, lane = (idx >> 3) & 63, kt = idx >> 9;
        dst[((size_t)ct * Kt + kt) * 512 + lane * 8 + e] =
            (_Float16)tile[kt * 32 + (lane >> 4) * 8 + e][lane & 15];
    }
}

// ---------------------------------------------------------------------------
// Kernel A: build mlp_input x[N,64] (obs[n%512] ++ latent_flat[n]) and
// h[N,128] = relu(x @ hw1 + hb1), stored as f16 (MFMA A operand).
// ---------------------------------------------------------------------------
__global__ __launch_bounds__(128)
void k_input_h(const float* __restrict__ obs, const float* __restrict__ latent,
               const float* __restrict__ hw1, const float* __restrict__ hb1,
               float* __restrict__ xbuf, _Float16* __restrict__ hf) {
    __shared__ float xs[16][DIM];
    int n0 = blockIdx.x * 16;
    int tid = threadIdx.x;
    for (int idx = tid; idx < 16 * DIM; idx += 128) {
        int r = idx >> 6, d = idx & 63;
        int n = n0 + r;
        // reference pairs obs[n % B] with latent_flat[n] (torch .repeat tiles
        // the batch dim; reshape(-1,DO) is row-major) — replicate exactly.
        float v = (d < DS) ? obs[(n & (BATCH - 1)) * DS + d]
                           : latent[(size_t)n * DO + (d - DS)];
        xs[r][d] = v;
        xbuf[(size_t)n * DIM + d] = v;
    }
    __syncthreads();
    int j = tid;  // 0..127
    float acc[16];
    float b = hb1[j];
#pragma unroll
    for (int r = 0; r < 16; ++r) acc[r] = b;
    for (int d = 0; d < DIM; ++d) {
        float w = hw1[d * HID + j];
#pragma unroll
        for (int r = 0; r < 16; ++r) acc[r] = fmaf(xs[r][d], w, acc[r]);
    }
#pragma unroll
    for (int r = 0; r < 16; ++r)
        hf[(size_t)(n0 + r) * HID + j] = (_Float16)fmaxf(acc[r], 0.f);
}

// ---------------------------------------------------------------------------
// Kernel B: LDS-staged tiled MFMA GEMM (m97 structure) + fused epilogue.
// Block = 128 rows x 8 d's (1024 cols). Per d-chunk: async-stage 32 KB of
// packed B into LDS, 2 barriers, 8 waves x 32 MFMA consuming it (8x B reuse).
// Each wave owns rows [wave*16,+16) x all 128 emb cols -> d-reduction stays
// in 32 regs; cross-block d-reduce via fp32 partials (8 groups).
// ---------------------------------------------------------------------------
__global__ __launch_bounds__(512, 4)
void k_hyper_mfma(const float* __restrict__ xbuf, const _Float16* __restrict__ hf,
                  const _Float16* __restrict__ w2p, const float* __restrict__ hb2,
                  float* __restrict__ partials) {
    __shared__ __align__(16) _Float16 Bs[8][4][512];  // 32 KB: [tile][kt][lane*8+e]
    __shared__ float xs[128][9];                      // 4.6 KB (pad 9: no conflicts)
    __shared__ float bias_s[DG * HID];                // 4 KB
    int b  = blockIdx.x;
    int rb = b & 63;        // row-tile:  rows [rb*128, +128)
    int dg = b >> 6;        // d-group:   d in [dg*8, +8)
    int tid = threadIdx.x;
    int wave = tid >> 6, lane = tid & 63;
    int l15 = lane & 15, quad = lane >> 4;
    int row0 = rb * 128;

    // one-time stage: x slice (fp32) + bias slice
    for (int i = tid; i < 128 * 8; i += 512) {
        int r = i >> 3, c = i & 7;
        xs[r][c] = xbuf[(size_t)(row0 + r) * DIM + dg * 8 + c];
    }
    for (int i = tid; i < DG * HID; i += 512)
        bias_s[i] = hb2[dg * (DG * HID) + i];

    // A-fragments: one-time global loads (16 rows per wave), persist in regs
    half8 af[4];
    {
        const _Float16* arow = hf + (size_t)(row0 + wave * 16 + l15) * HID;
#pragma unroll
        for (int ks = 0; ks < 4; ++ks)
            af[ks] = *(const half8*)(arow + ks * 32 + quad * 8);
    }

    float emb_acc[8][4];
#pragma unroll
    for (int ct2 = 0; ct2 < 8; ++ct2)
#pragma unroll
        for (int reg = 0; reg < 4; ++reg) emb_acc[ct2][reg] = 0.f;

    for (int d8 = 0; d8 < DG; ++d8) {
        // stage B for this d: 8 tiles (32 KB); wave w stages tile w (4 x 1 KB)
        {
            int ctg = (dg * DG + d8) * 8 + wave;
            const _Float16* src = w2p + (size_t)ctg * 2048 + lane * 8;
            _Float16* dst = &Bs[wave][0][0];
#pragma unroll
            for (int kt = 0; kt < 4; ++kt)
                async_ld16(dst + kt * 512, src + kt * 512);
        }
        __syncthreads();   // staging complete (compiler drains vmcnt)

        float xv[4];
#pragma unroll
        for (int reg = 0; reg < 4; ++reg)
            xv[reg] = xs[wave * 16 + quad * 4 + reg][d8];

#pragma unroll
        for (int ct2 = 0; ct2 < 8; ++ct2) {
            float bb = bias_s[d8 * HID + ct2 * 16 + l15];
            floatx4 acc = {bb, bb, bb, bb};
#pragma unroll
            for (int ks = 0; ks < 4; ++ks) {
                half8 bfr = *(const half8*)&Bs[ct2][ks][lane * 8];
                acc = __builtin_amdgcn_mfma_f32_16x16x32_f16(af[ks], bfr, acc, 0, 0, 0);
            }
            // D: row = wave*16 + quad*4 + reg, col = ct2*16 + l15
#pragma unroll
            for (int reg = 0; reg < 4; ++reg)
                emb_acc[ct2][reg] = fmaf(xv[reg], fmaxf(acc[reg], 0.f),
                                         emb_acc[ct2][reg]);
        }
        __syncthreads();   // done consuming Bs; safe to restage
    }

    // write fp32 partial emb for this d-group
    float* pout = partials + (size_t)dg * NROWS * HID
                + (size_t)(row0 + wave * 16) * HID;
#pragma unroll
    for (int ct2 = 0; ct2 < 8; ++ct2)
#pragma unroll
        for (int reg = 0; reg < 4; ++reg)
            pout[(size_t)(quad * 4 + reg) * HID + ct2 * 16 + l15] = emb_acc[ct2][reg];
}

// ---------------------------------------------------------------------------
// Kernel R: emb = tanh(sum of 8 partials), f16; fused batch-mean (k_mean gone)
// ---------------------------------------------------------------------------
__global__ __launch_bounds__(256)
void k_reduce(const float* __restrict__ partials, _Float16* __restrict__ embf,
              _Float16* __restrict__ emeanf) {
    __shared__ float el[16][HID];
    int g = blockIdx.x;   // batch index 0..511 (rows g*16..+16 = group)
    int tid = threadIdx.x;
    for (int i = tid; i < 16 * HID; i += 256) {
        int r = i >> 7, c = i & 127;
        size_t off = (size_t)(g * 16 + r) * HID + c;
        float s = 0.f;
#pragma unroll
        for (int p = 0; p < 8; ++p)
            s += partials[(size_t)p * NROWS * HID + off];
        float e = tanhf(s);
        embf[off] = (_Float16)e;
        el[r][c] = e;
    }
    __syncthreads();
    if (tid < HID) {
        float s = 0.f;
#pragma unroll
        for (int r = 0; r < 16; ++r) s += el[r][tid];
        emeanf[(size_t)g * HID + tid] = (_Float16)(s * (1.f / 16));
    }
}

// ---------------------------------------------------------------------------
// Kernel T (fused tail), 512 threads / 8 waves (2x occupancy vs r3):
//   vals = relu(relu(emb@vw1+b)@vw2+b)                 [MFMA, regs]
//   scores = relu(relu([emb|mean]@aw1+b)@aw2+b)@aw3+b  [MFMA + dot]
//   att = softmax over 16-row group; out[g] = sum_a att*vals
// ---------------------------------------------------------------------------
__global__ __launch_bounds__(512)
void k_tail(const _Float16* __restrict__ embf, const _Float16* __restrict__ emeanf,
            const _Float16* __restrict__ vw1p, const float* __restrict__ vb1,
            const _Float16* __restrict__ vw2p, const float* __restrict__ vb2,
            const _Float16* __restrict__ aw1p, const float* __restrict__ ab1,
            const _Float16* __restrict__ aw2p, const float* __restrict__ ab2,
            const float* __restrict__ aw3, const float* __restrict__ ab3,
            float* __restrict__ out) {
    __shared__ _Float16 embs[32][LSTR];
    __shared__ _Float16 means[32][LSTR];
    __shared__ _Float16 tAs[32][LSTR];
    __shared__ _Float16 tBs[32][LSTR];
    __shared__ float satt[32];
    __shared__ float att[32];
    __shared__ float scr[32][16];
    __shared__ float outacc[2][HID];
    int n0 = blockIdx.x * 32;
    int tid = threadIdx.x;
    int wave = tid >> 6, lane = tid & 63, l15 = lane & 15, quad = lane >> 4;
    int ct = wave;   // wave owns col-tile ct of 8

    for (int i = tid; i < 32 * 16; i += 512) {
        int r = i >> 4, c8 = (i & 15) * 8;
        *(half8*)&embs[r][c8]  = *(const half8*)(embf  + (size_t)(n0 + r) * HID + c8);
        // mean_rep[n] = emb_mean[n % 512] (torch .repeat tiling) — exact.
        *(half8*)&means[r][c8] = *(const half8*)(emeanf + (size_t)((n0 & 511) + r) * HID + c8);
    }
    __syncthreads();

    half8 av[2][4], amean[2][4];
#pragma unroll
    for (int rt = 0; rt < 2; ++rt)
#pragma unroll
        for (int ks = 0; ks < 4; ++ks) {
            av[rt][ks]    = *(const half8*)&embs[rt * 16 + l15][ks * 32 + quad * 8];
            amean[rt][ks] = *(const half8*)&means[rt * 16 + l15][ks * 32 + quad * 8];
        }

    // ---- v1: t1 = relu(emb @ vw1 + vb1) ----
    floatx4 acc[2];
    {
        float bb = vb1[ct * 16 + l15];
#pragma unroll
        for (int rt = 0; rt < 2; ++rt) acc[rt] = (floatx4){bb, bb, bb, bb};
    }
#pragma unroll
    for (int ks = 0; ks < 4; ++ks) {
        half8 bfr = *(const half8*)(vw1p + ((size_t)ct * 4 + ks) * 512 + lane * 8);
#pragma unroll
        for (int rt = 0; rt < 2; ++rt)
            acc[rt] = __builtin_amdgcn_mfma_f32_16x16x32_f16(av[rt][ks], bfr, acc[rt], 0, 0, 0);
    }
#pragma unroll
    for (int rt = 0; rt < 2; ++rt)
#pragma unroll
        for (int reg = 0; reg < 4; ++reg)
            tAs[rt * 16 + quad * 4 + reg][ct * 16 + l15] =
                (_Float16)fmaxf(acc[rt][reg], 0.f);
    __syncthreads();

    half8 at[2][4];
#pragma unroll
    for (int rt = 0; rt < 2; ++rt)
#pragma unroll
        for (int ks = 0; ks < 4; ++ks)
            at[rt][ks] = *(const half8*)&tAs[rt * 16 + l15][ks * 32 + quad * 8];

    // ---- v2: vals = relu(t1 @ vw2 + vb2), kept in registers ----
    floatx4 vacc[2];
    {
        float bb = vb2[ct * 16 + l15];
#pragma unroll
        for (int rt = 0; rt < 2; ++rt) vacc[rt] = (floatx4){bb, bb, bb, bb};
    }
#pragma unroll
    for (int ks = 0; ks < 4; ++ks) {
        half8 bfr = *(const half8*)(vw2p + ((size_t)ct * 4 + ks) * 512 + lane * 8);
#pragma unroll
        for (int rt = 0; rt < 2; ++rt)
            vacc[rt] = __builtin_amdgcn_mfma_f32_16x16x32_f16(at[rt][ks], bfr, vacc[rt], 0, 0, 0);
    }

    // ---- a1: ta1 = relu([emb|mean] @ aw1 + ab1), K=256 ----
    floatx4 aacc[2];
    {
        float bb = ab1[ct * 16 + l15];
#pragma unroll
        for (int rt = 0; rt < 2; ++rt) aacc[rt] = (floatx4){bb, bb, bb, bb};
    }
#pragma unroll
    for (int ks = 0; ks < 8; ++ks) {
        half8 bfr = *(const half8*)(aw1p + ((size_t)ct * 8 + ks) * 512 + lane * 8);
#pragma unroll
        for (int rt = 0; rt < 2; ++rt) {
            half8 a = (ks < 4) ? av[rt][ks] : amean[rt][ks - 4];
            aacc[rt] = __builtin_amdgcn_mfma_f32_16x16x32_f16(a, bfr, aacc[rt], 0, 0, 0);
        }
    }
#pragma unroll
    for (int rt = 0; rt < 2; ++rt)
#pragma unroll
        for (int reg = 0; reg < 4; ++reg)
            tBs[rt * 16 + quad * 4 + reg][ct * 16 + l15] =
                (_Float16)fmaxf(aacc[rt][reg], 0.f);
    __syncthreads();

    half8 aa[2][4];
#pragma unroll
    for (int rt = 0; rt < 2; ++rt)
#pragma unroll
        for (int ks = 0; ks < 4; ++ks)
            aa[rt][ks] = *(const half8*)&tBs[rt * 16 + l15][ks * 32 + quad * 8];

    // ---- a2: t2 = relu(ta1 @ aw2 + ab2) -> tAs ----
    floatx4 a2acc[2];
    {
        float bb = ab2[ct * 16 + l15];
#pragma unroll
        for (int rt = 0; rt < 2; ++rt) a2acc[rt] = (floatx4){bb, bb, bb, bb};
    }
#pragma unroll
    for (int ks = 0; ks < 4; ++ks) {
        half8 bfr = *(const half8*)(aw2p + ((size_t)ct * 4 + ks) * 512 + lane * 8);
#pragma unroll
        for (int rt = 0; rt < 2; ++rt)
            a2acc[rt] = __builtin_amdgcn_mfma_f32_16x16x32_f16(aa[rt][ks], bfr, a2acc[rt], 0, 0, 0);
    }
#pragma unroll
    for (int rt = 0; rt < 2; ++rt)
#pragma unroll
        for (int reg = 0; reg < 4; ++reg)
            tAs[rt * 16 + quad * 4 + reg][ct * 16 + l15] =
                (_Float16)fmaxf(a2acc[rt][reg], 0.f);
    __syncthreads();

    // ---- scores: s[r] = t2[r,:] . aw3 + ab3 ----
    {
        int r = tid >> 4, ch = tid & 15;
        float p = 0.f;
#pragma unroll
        for (int k = 0; k < 8; ++k)
            p += (float)tAs[r][ch * 8 + k] * aw3[ch * 8 + k];
        scr[r][ch] = p;
    }
    __syncthreads();
    if (tid < 32) {
        float s = ab3[0];
#pragma unroll
        for (int ch = 0; ch < 16; ++ch) s += scr[tid][ch];
        satt[tid] = s;
    }
    __syncthreads();
    if (tid < 32) {
        int g = tid & ~15;
        float m = -1e30f;
#pragma unroll
        for (int a = 0; a < 16; ++a) m = fmaxf(m, satt[g + a]);
        float S = 0.f;
#pragma unroll
        for (int a = 0; a < 16; ++a) S += expf(satt[g + a] - m);
        att[tid] = expf(satt[tid] - m) / S;
    }
    __syncthreads();

    // ---- weighted sum: out[g, col] = sum_a att[a] * vals[a, col] ----
#pragma unroll
    for (int rt = 0; rt < 2; ++rt) {
        float p = 0.f;
#pragma unroll
        for (int reg = 0; reg < 4; ++reg)
            p += att[rt * 16 + quad * 4 + reg] * fmaxf(vacc[rt][reg], 0.f);
        p += __shfl_xor(p, 16, 64);
        p += __shfl_xor(p, 32, 64);
        if (quad == 0) outacc[rt][ct * 16 + l15] = p;
    }
    __syncthreads();
    if (tid < 256) {
        int rt = tid >> 7, col = tid & 127;
        out[(size_t)((n0 >> 4) + rt) * HID + col] = outacc[rt][col];
    }
}

// ---------------------------------------------------------------------------
extern "C" void kernel_launch(void* const* d_in, const int* in_sizes, int n_in,
                              void* d_out, int out_size, void* d_ws, size_t ws_size,
                              hipStream_t stream) {
    const float* obs = (const float*)d_in[0];
    const float* lat = (const float*)d_in[1];
    const float* hw1 = (const float*)d_in[2];
    const float* hb1 = (const float*)d_in[3];
    const float* hw2 = (const float*)d_in[4];
    const float* hb2 = (const float*)d_in[5];
    const float* vw1 = (const float*)d_in[6];
    const float* vb1 = (const float*)d_in[7];
    const float* vw2 = (const float*)d_in[8];
    const float* vb2 = (const float*)d_in[9];
    const float* aw1 = (const float*)d_in[10];
    const float* ab1 = (const float*)d_in[11];
    const float* aw2 = (const float*)d_in[12];
    const float* ab2 = (const float*)d_in[13];
    const float* aw3 = (const float*)d_in[14];
    const float* ab3 = (const float*)d_in[15];
    float* out = (float*)d_out;

    char* ws = (char*)d_ws;
    float*     xbuf   = (float*)ws;     ws += (size_t)NROWS * DIM * 4;     // 2 MB
    _Float16*  hf     = (_Float16*)ws;  ws += (size_t)NROWS * HID * 2;     // 2 MB
    _Float16*  w2p    = (_Float16*)ws;  ws += (size_t)WCOLS * HID * 2;     // 2 MB
    _Float16*  embf   = (_Float16*)ws;  ws += (size_t)NROWS * HID * 2;     // 2 MB
    _Float16*  emeanf = (_Float16*)ws;  ws += (size_t)BATCH * HID * 2;     // 128 KB
    _Float16*  vw1p   = (_Float16*)ws;  ws += (size_t)HID * HID * 2;       // 32 KB
    _Float16*  vw2p   = (_Float16*)ws;  ws += (size_t)HID * HID * 2;
    _Float16*  aw1p   = (_Float16*)ws;  ws += (size_t)2 * HID * HID * 2;   // 64 KB
    _Float16*  aw2p   = (_Float16*)ws;  ws += (size_t)HID * HID * 2;
    float*     partials = (float*)ws;   ws += (size_t)8 * NROWS * HID * 4; // 32 MB

    hipLaunchKernelGGL(k_pack, dim3(544), dim3(256), 0, stream,
                       hw2, vw1, vw2, aw1, aw2, w2p, vw1p, vw2p, aw1p, aw2p);
    hipLaunchKernelGGL(k_input_h, dim3(NROWS / 16), dim3(128), 0, stream,
                       obs, lat, hw1, hb1, xbuf, hf);
    hipLaunchKernelGGL(k_hyper_mfma, dim3(512), dim3(512), 0, stream,
                       xbuf, hf, w2p, hb2, partials);
    hipLaunchKernelGGL(k_reduce, dim3(BATCH), dim3(256), 0, stream,
                       partials, embf, emeanf);
    hipLaunchKernelGGL(k_tail, dim3(NROWS / 32), dim3(512), 0, stream,
                       embf, emeanf, vw1p, vb1, vw2p, vb2,
                       aw1p, ab1, aw2p, ab2, aw3, ab3, out);
}